// Round 1
// baseline (90103.668 us; speedup 1.0000x reference)
//
#include <hip/hip_runtime.h>

#define VOCAB  30
#define HID    512
#define KS     128
#define VS     128
#define EMB    256
#define TT     1000
#define NB     256
#define MAXLEN 250

// ws layout (floats)
#define NH (NB*HID)          // 131072
#define NK (NB*KS)           // 32768
#define OFF_CTX (6*NH + 3*NK)    // h1[2],c1,h2[2],c2,h3[2],c3
#define WS_TOTAL (OFF_CTX + NK)

__device__ __forceinline__ float sigmoidf_(float x){ return 1.0f/(1.0f+__expf(-x)); }

__global__ __launch_bounds__(256)
void init_kernel(float* __restrict__ ws, const float* __restrict__ values){
    int i = blockIdx.x*256 + threadIdx.x;
    if (i >= WS_TOTAL) return;
    if (i < OFF_CTX) ws[i] = 0.0f;
    else ws[i] = values[(size_t)(TT-1)*NB*VS + (i - OFF_CTX)];  // ctx = values[-1]
}

// Fused gates-GEMM + LSTM cell update.
// gates[n, g*H+h] = x[n,:] @ Wx[g*H+h,:] + h_old[n,:] @ Wh[g*H+h,:] + bx + bh
// Block tile: 64 n x (16 h x 4 gates). Grid: (H/16, NB/64).
// MODE 0: x = [embed_W[text[n,t]], ctx[n]]  (KX=384); MODE 1: x = xbuf (N,KX)
template<int H, int KX, int KH, int MODE>
__global__ __launch_bounds__(256)
void lstm_kernel(const float* __restrict__ Wx, const float* __restrict__ Wh,
                 const float* __restrict__ bx, const float* __restrict__ bh,
                 const float* __restrict__ xbuf, const float* __restrict__ embW,
                 const int* __restrict__ text, int step,
                 const float* __restrict__ hread, float* __restrict__ hwrite,
                 float* __restrict__ cbuf)
{
    __shared__ __align__(16) float Xs[16][68];   // [k][n], padded
    __shared__ __align__(16) float Ws[16][68];   // [k][col], padded
    __shared__ float Gs[64][65];                 // gates [col][n]

    const int tid = threadIdx.x;
    const int h0  = blockIdx.x * 16;
    const int n0  = blockIdx.y * 64;

    // staging role: row sr (n or col), 4 consecutive k at sk
    const int sr = tid >> 2;
    const int sk = (tid & 3) << 2;
    const int wrow = (sr >> 4) * H + h0 + (sr & 15);   // W row for col sr
    const int n  = n0 + sr;

    // compute role: 4 n x 4 cols per thread
    const int tn4 = (tid & 15) * 4;
    const int tc4 = (tid >> 4) * 4;

    float acc[4][4];
    #pragma unroll
    for (int i=0;i<4;i++){
        #pragma unroll
        for (int j=0;j<4;j++) acc[i][j]=0.0f;
    }

    for (int k0 = 0; k0 < KX + KH; k0 += 16) {
        const int kb = k0 + sk;
        float4 xv, wv;
        if (k0 < KX) {
            if constexpr (MODE == 0) {
                if (kb < EMB) {
                    int idx = text[n * MAXLEN + step];
                    xv = *(const float4*)(embW + idx*EMB + kb);
                } else {
                    xv = *(const float4*)(xbuf + n*VS + (kb - EMB));
                }
            } else {
                xv = *(const float4*)(xbuf + n*KX + kb);
            }
            wv = *(const float4*)(Wx + wrow*KX + kb);
        } else {
            const int kh = kb - KX;
            xv = *(const float4*)(hread + n*KH + kh);
            wv = *(const float4*)(Wh + wrow*KH + kh);
        }
        Xs[sk+0][sr]=xv.x; Xs[sk+1][sr]=xv.y; Xs[sk+2][sr]=xv.z; Xs[sk+3][sr]=xv.w;
        Ws[sk+0][sr]=wv.x; Ws[sk+1][sr]=wv.y; Ws[sk+2][sr]=wv.z; Ws[sk+3][sr]=wv.w;
        __syncthreads();
        #pragma unroll
        for (int kk=0;kk<16;kk++){
            float4 xr = *(const float4*)&Xs[kk][tn4];
            float4 wr = *(const float4*)&Ws[kk][tc4];
            acc[0][0] += wr.x*xr.x; acc[0][1] += wr.x*xr.y; acc[0][2] += wr.x*xr.z; acc[0][3] += wr.x*xr.w;
            acc[1][0] += wr.y*xr.x; acc[1][1] += wr.y*xr.y; acc[1][2] += wr.y*xr.z; acc[1][3] += wr.y*xr.w;
            acc[2][0] += wr.z*xr.x; acc[2][1] += wr.z*xr.y; acc[2][2] += wr.z*xr.z; acc[2][3] += wr.z*xr.w;
            acc[3][0] += wr.w*xr.x; acc[3][1] += wr.w*xr.y; acc[3][2] += wr.w*xr.z; acc[3][3] += wr.w*xr.w;
        }
        __syncthreads();
    }

    // bias + park gates in LDS so each (h,n) cell sees all 4 gates
    #pragma unroll
    for (int ci=0; ci<4; ci++){
        const int c = tc4 + ci;
        const int row = (c >> 4) * H + h0 + (c & 15);
        const float b = bx[row] + bh[row];
        #pragma unroll
        for (int ni=0; ni<4; ni++) Gs[c][tn4+ni] = acc[ci][ni] + b;
    }
    __syncthreads();

    for (int p = tid; p < 16*64; p += 256){
        const int hl = p & 15, nl = p >> 4;
        const float gi = Gs[     hl][nl];
        const float gf = Gs[16 + hl][nl];
        const float gg = Gs[32 + hl][nl];
        const float go = Gs[48 + hl][nl];
        const int gn = n0 + nl, gh = h0 + hl;
        const float cold = cbuf[gn*H + gh];
        const float cn = sigmoidf_(gf)*cold + sigmoidf_(gi)*tanhf(gg);
        const float hn = sigmoidf_(go)*tanhf(cn);
        cbuf[gn*H + gh] = cn;
        hwrite[gn*H + gh] = hn;
    }
}

// One block per n: energy -> masked softmax (writes attns) -> ctx -> pred (writes preds)
__global__ __launch_bounds__(256)
void attn_pred_kernel(const float* __restrict__ keys, const float* __restrict__ values,
                      const int* __restrict__ seqlen, const float* __restrict__ h3,
                      const float* __restrict__ linW, const float* __restrict__ linb,
                      const float* __restrict__ charW, const float* __restrict__ charb,
                      float* __restrict__ ctx, float* __restrict__ out, int step)
{
    __shared__ float es[TT];
    __shared__ float red8[8];
    __shared__ float cpart[2][128];
    __shared__ float cat[256];
    __shared__ float mid[128];

    const int tid  = threadIdx.x;
    const int n    = blockIdx.x;
    const int wave = tid >> 6, lane = tid & 63;

    const float2 hv = *(const float2*)(h3 + n*KS + lane*2);
    const int L = seqlen[n];

    // energy[t] = dot(keys[t,n,:], h3[n,:]); one wave per t
    for (int t = wave; t < TT; t += 4) {
        const float2 kv = *(const float2*)(keys + ((size_t)t*NB + n)*KS + lane*2);
        float d = kv.x*hv.x + kv.y*hv.y;
        #pragma unroll
        for (int off=32; off; off>>=1) d += __shfl_xor(d, off, 64);
        if (lane == 0) es[t] = (t < L) ? d : -1e9f;
    }
    __syncthreads();

    // softmax over 1000
    float m = -3e38f;
    for (int t = tid; t < TT; t += 256) m = fmaxf(m, es[t]);
    #pragma unroll
    for (int off=32; off; off>>=1) m = fmaxf(m, __shfl_xor(m, off, 64));
    if (lane == 0) red8[wave] = m;
    __syncthreads();
    m = fmaxf(fmaxf(red8[0],red8[1]), fmaxf(red8[2],red8[3]));

    float s = 0.0f;
    for (int t = tid; t < TT; t += 256) { float p = __expf(es[t]-m); es[t] = p; s += p; }
    #pragma unroll
    for (int off=32; off; off>>=1) s += __shfl_xor(s, off, 64);
    if (lane == 0) red8[4+wave] = s;
    __syncthreads();
    const float inv = 1.0f/(red8[4]+red8[5]+red8[6]+red8[7]);

    float* attn_out = out + (size_t)NB*MAXLEN*VOCAB + ((size_t)step*NB + n)*TT;
    for (int t = tid; t < TT; t += 256) { float a = es[t]*inv; es[t] = a; attn_out[t] = a; }
    __syncthreads();

    // ctx[n,v] = sum_t attn[t] * values[t,n,v]; t split in 2 halves
    const int v = tid & 127, half = tid >> 7;
    float ca = 0.0f;
    for (int t = half*500; t < half*500 + 500; ++t)
        ca += es[t] * values[((size_t)t*NB + n)*VS + v];
    cpart[half][v] = ca;
    __syncthreads();
    if (tid < 128) {
        const float cv = cpart[0][tid] + cpart[1][tid];
        ctx[n*VS + tid] = cv;
        cat[tid]       = h3[n*KS + tid];
        cat[128 + tid] = cv;
    }
    __syncthreads();

    // pred = ([h3, ctx] @ linW^T + linb) @ charW^T + charb
    if (tid < 128) {
        float a = linb[tid];
        const float* w = linW + tid*(KS+VS);
        #pragma unroll 8
        for (int k=0;k<KS+VS;k++) a += w[k]*cat[k];
        mid[tid] = a;
    }
    __syncthreads();
    if (tid < VOCAB) {
        float a = charb[tid];
        const float* w = charW + tid*KS;
        #pragma unroll 8
        for (int k=0;k<KS;k++) a += w[k]*mid[k];
        out[((size_t)n*MAXLEN + step)*VOCAB + tid] = a;
    }
}

extern "C" void kernel_launch(void* const* d_in, const int* in_sizes, int n_in,
                              void* d_out, int out_size, void* d_ws, size_t ws_size,
                              hipStream_t stream)
{
    const float* keys   = (const float*)d_in[0];
    const float* values = (const float*)d_in[1];
    const int*   seqlen = (const int*)  d_in[2];
    const int*   text   = (const int*)  d_in[3];
    const float* embW   = (const float*)d_in[4];
    const float* w_ih1  = (const float*)d_in[5];
    const float* w_hh1  = (const float*)d_in[6];
    const float* b_ih1  = (const float*)d_in[7];
    const float* b_hh1  = (const float*)d_in[8];
    const float* w_ih2  = (const float*)d_in[9];
    const float* w_hh2  = (const float*)d_in[10];
    const float* b_ih2  = (const float*)d_in[11];
    const float* b_hh2  = (const float*)d_in[12];
    const float* w_ih3  = (const float*)d_in[13];
    const float* w_hh3  = (const float*)d_in[14];
    const float* b_ih3  = (const float*)d_in[15];
    const float* b_hh3  = (const float*)d_in[16];
    const float* linW   = (const float*)d_in[17];
    const float* linb   = (const float*)d_in[18];
    const float* charW  = (const float*)d_in[19];
    const float* charb  = (const float*)d_in[20];
    float* out = (float*)d_out;
    float* ws  = (float*)d_ws;

    float* h1  = ws;              // 2*NH (double buffered)
    float* c1  = h1 + 2*NH;       // NH
    float* h2  = c1 + NH;         // 2*NH
    float* c2  = h2 + 2*NH;       // NH
    float* h3  = c2 + NH;         // 2*NK
    float* c3  = h3 + 2*NK;       // NK
    float* ctx = c3 + NK;         // NK

    init_kernel<<<(WS_TOTAL + 255)/256, 256, 0, stream>>>(ws, (const float*)d_in[1]);

    for (int t = 0; t < MAXLEN; ++t) {
        const int cur = t & 1, nxt = cur ^ 1;
        lstm_kernel<HID, EMB+VS, HID, 0><<<dim3(HID/16, NB/64), 256, 0, stream>>>(
            w_ih1, w_hh1, b_ih1, b_hh1, ctx, embW, text, t,
            h1 + cur*NH, h1 + nxt*NH, c1);
        lstm_kernel<HID, HID, HID, 1><<<dim3(HID/16, NB/64), 256, 0, stream>>>(
            w_ih2, w_hh2, b_ih2, b_hh2, h1 + nxt*NH, nullptr, nullptr, t,
            h2 + cur*NH, h2 + nxt*NH, c2);
        lstm_kernel<KS, HID, KS, 1><<<dim3(KS/16, NB/64), 256, 0, stream>>>(
            w_ih3, w_hh3, b_ih3, b_hh3, h2 + nxt*NH, nullptr, nullptr, t,
            h3 + cur*NK, h3 + nxt*NK, c3);
        attn_pred_kernel<<<NB, 256, 0, stream>>>(
            keys, values, seqlen, h3 + nxt*NK,
            linW, linb, charW, charb, ctx, out, t);
    }
}

// Round 2
// 54308.191 us; speedup vs baseline: 1.6591x; 1.6591x over previous
//
#include <hip/hip_runtime.h>

#define VOCAB  30
#define HID    512
#define KS     128
#define VS     128
#define EMB    256
#define TT     1000
#define NB     256
#define MAXLEN 250

// ws layout (floats)
#define NH (NB*HID)          // 131072
#define NK (NB*KS)           // 32768
#define OFF_CTX (6*NH + 3*NK)    // h1[2],c1,h2[2],c2,h3[2],c3
#define WS_TOTAL (OFF_CTX + NK)
#define STATE_BYTES ((size_t)WS_TOTAL * 4)     // 3,670,016 (16B aligned)
#define VBF_BYTES   ((size_t)TT * NB * VS * 2) // 65,536,000

__device__ __forceinline__ float sigmoidf_(float x){ return 1.0f/(1.0f+__expf(-x)); }

__device__ __forceinline__ unsigned short f2bf_(float x){
    unsigned int u = __float_as_uint(x);
    return (unsigned short)((u + 0x7fffu + ((u >> 16) & 1u)) >> 16);  // RNE
}

__global__ __launch_bounds__(256)
void init_kernel(float* __restrict__ ws, const float* __restrict__ values){
    int i = blockIdx.x*256 + threadIdx.x;
    if (i >= WS_TOTAL) return;
    if (i < OFF_CTX) ws[i] = 0.0f;
    else ws[i] = values[(size_t)(TT-1)*NB*VS + (i - OFF_CTX)];  // ctx = values[-1]
}

__global__ __launch_bounds__(256)
void conv_bf16_kernel(const float* __restrict__ src, unsigned short* __restrict__ dst, int n4){
    int i = blockIdx.x*256 + threadIdx.x;
    if (i >= n4) return;
    float4 v = ((const float4*)src)[i];
    ushort4 o;
    o.x = f2bf_(v.x); o.y = f2bf_(v.y); o.z = f2bf_(v.z); o.w = f2bf_(v.w);
    ((ushort4*)dst)[i] = o;
}

// Fused gates-GEMM + LSTM cell update (unchanged from R1 — known correct).
template<int H, int KX, int KH, int MODE>
__global__ __launch_bounds__(256)
void lstm_kernel(const float* __restrict__ Wx, const float* __restrict__ Wh,
                 const float* __restrict__ bx, const float* __restrict__ bh,
                 const float* __restrict__ xbuf, const float* __restrict__ embW,
                 const int* __restrict__ text, int step,
                 const float* __restrict__ hread, float* __restrict__ hwrite,
                 float* __restrict__ cbuf)
{
    __shared__ __align__(16) float Xs[16][68];
    __shared__ __align__(16) float Ws[16][68];
    __shared__ float Gs[64][65];

    const int tid = threadIdx.x;
    const int h0  = blockIdx.x * 16;
    const int n0  = blockIdx.y * 64;

    const int sr = tid >> 2;
    const int sk = (tid & 3) << 2;
    const int wrow = (sr >> 4) * H + h0 + (sr & 15);
    const int n  = n0 + sr;

    const int tn4 = (tid & 15) * 4;
    const int tc4 = (tid >> 4) * 4;

    float acc[4][4];
    #pragma unroll
    for (int i=0;i<4;i++){
        #pragma unroll
        for (int j=0;j<4;j++) acc[i][j]=0.0f;
    }

    for (int k0 = 0; k0 < KX + KH; k0 += 16) {
        const int kb = k0 + sk;
        float4 xv, wv;
        if (k0 < KX) {
            if constexpr (MODE == 0) {
                if (kb < EMB) {
                    int idx = text[n * MAXLEN + step];
                    xv = *(const float4*)(embW + idx*EMB + kb);
                } else {
                    xv = *(const float4*)(xbuf + n*VS + (kb - EMB));
                }
            } else {
                xv = *(const float4*)(xbuf + n*KX + kb);
            }
            wv = *(const float4*)(Wx + wrow*KX + kb);
        } else {
            const int kh = kb - KX;
            xv = *(const float4*)(hread + n*KH + kh);
            wv = *(const float4*)(Wh + wrow*KH + kh);
        }
        Xs[sk+0][sr]=xv.x; Xs[sk+1][sr]=xv.y; Xs[sk+2][sr]=xv.z; Xs[sk+3][sr]=xv.w;
        Ws[sk+0][sr]=wv.x; Ws[sk+1][sr]=wv.y; Ws[sk+2][sr]=wv.z; Ws[sk+3][sr]=wv.w;
        __syncthreads();
        #pragma unroll
        for (int kk=0;kk<16;kk++){
            float4 xr = *(const float4*)&Xs[kk][tn4];
            float4 wr = *(const float4*)&Ws[kk][tc4];
            acc[0][0] += wr.x*xr.x; acc[0][1] += wr.x*xr.y; acc[0][2] += wr.x*xr.z; acc[0][3] += wr.x*xr.w;
            acc[1][0] += wr.y*xr.x; acc[1][1] += wr.y*xr.y; acc[1][2] += wr.y*xr.z; acc[1][3] += wr.y*xr.w;
            acc[2][0] += wr.z*xr.x; acc[2][1] += wr.z*xr.y; acc[2][2] += wr.z*xr.z; acc[2][3] += wr.z*xr.w;
            acc[3][0] += wr.w*xr.x; acc[3][1] += wr.w*xr.y; acc[3][2] += wr.w*xr.z; acc[3][3] += wr.w*xr.w;
        }
        __syncthreads();
    }

    #pragma unroll
    for (int ci=0; ci<4; ci++){
        const int c = tc4 + ci;
        const int row = (c >> 4) * H + h0 + (c & 15);
        const float b = bx[row] + bh[row];
        #pragma unroll
        for (int ni=0; ni<4; ni++) Gs[c][tn4+ni] = acc[ci][ni] + b;
    }
    __syncthreads();

    for (int p = tid; p < 16*64; p += 256){
        const int hl = p & 15, nl = p >> 4;
        const float gi = Gs[     hl][nl];
        const float gf = Gs[16 + hl][nl];
        const float gg = Gs[32 + hl][nl];
        const float go = Gs[48 + hl][nl];
        const int gn = n0 + nl, gh = h0 + hl;
        const float cold = cbuf[gn*H + gh];
        const float cn = sigmoidf_(gf)*cold + sigmoidf_(gi)*tanhf(gg);
        const float hn = sigmoidf_(go)*tanhf(cn);
        cbuf[gn*H + gh] = cn;
        hwrite[gn*H + gh] = hn;
    }
}

// One block per n, 512 threads (8 waves).
// BF=1: values are bf16 (raw ushort); BF=0: fp32 fallback.
template<int BF>
__global__ __launch_bounds__(512)
void attn_pred_kernel(const float* __restrict__ keys, const void* __restrict__ values_v,
                      const int* __restrict__ seqlen, const float* __restrict__ h3,
                      const float* __restrict__ linW, const float* __restrict__ linb,
                      const float* __restrict__ charW, const float* __restrict__ charb,
                      float* __restrict__ ctx, float* __restrict__ out, int step)
{
    __shared__ float es[TT];
    __shared__ float redm[8], reds[8];
    __shared__ float cpart[8][128];
    __shared__ float cat[256];
    __shared__ float mid[128];

    const int tid  = threadIdx.x;
    const int n    = blockIdx.x;
    const int wave = tid >> 6, lane = tid & 63;

    const float2 hv = *(const float2*)(h3 + n*KS + lane*2);
    const int L = seqlen[n];

    // energy: each wave does 4 consecutive t per iter (independent reduce chains for ILP)
    for (int t0 = wave*4; t0 < TT; t0 += 32) {
        const float2* kp = (const float2*)(keys + ((size_t)t0*NB + n)*KS) + lane;
        const size_t rs = (size_t)NB*KS/2;   // float2 stride between t rows
        float2 k0 = kp[0], k1 = kp[rs], k2 = kp[2*rs], k3 = kp[3*rs];
        float d0 = k0.x*hv.x + k0.y*hv.y;
        float d1 = k1.x*hv.x + k1.y*hv.y;
        float d2 = k2.x*hv.x + k2.y*hv.y;
        float d3 = k3.x*hv.x + k3.y*hv.y;
        #pragma unroll
        for (int off=32; off; off>>=1){
            d0 += __shfl_xor(d0, off, 64);
            d1 += __shfl_xor(d1, off, 64);
            d2 += __shfl_xor(d2, off, 64);
            d3 += __shfl_xor(d3, off, 64);
        }
        if (lane == 0){
            es[t0+0] = (t0+0 < L) ? d0 : -1e9f;
            es[t0+1] = (t0+1 < L) ? d1 : -1e9f;
            es[t0+2] = (t0+2 < L) ? d2 : -1e9f;
            es[t0+3] = (t0+3 < L) ? d3 : -1e9f;
        }
    }
    __syncthreads();

    // softmax over 1000
    float m = -3e38f;
    for (int t = tid; t < TT; t += 512) m = fmaxf(m, es[t]);
    #pragma unroll
    for (int off=32; off; off>>=1) m = fmaxf(m, __shfl_xor(m, off, 64));
    if (lane == 0) redm[wave] = m;
    __syncthreads();
    m = redm[0];
    #pragma unroll
    for (int w=1; w<8; ++w) m = fmaxf(m, redm[w]);

    float s = 0.0f;
    for (int t = tid; t < TT; t += 512) { float p = __expf(es[t]-m); es[t] = p; s += p; }
    #pragma unroll
    for (int off=32; off; off>>=1) s += __shfl_xor(s, off, 64);
    if (lane == 0) reds[wave] = s;
    __syncthreads();
    s = reds[0];
    #pragma unroll
    for (int w=1; w<8; ++w) s += reds[w];
    const float inv = 1.0f / s;

    float* attn_out = out + (size_t)NB*MAXLEN*VOCAB + ((size_t)step*NB + n)*TT;
    for (int t = tid; t < TT; t += 512) { float a = es[t]*inv; es[t] = a; attn_out[t] = a; }
    __syncthreads();

    // ctx: wave w handles t = w + 8*j; lane covers v = {lane*2, lane*2+1}
    float cax = 0.0f, cay = 0.0f;
    if constexpr (BF) {
        const unsigned short* vals = (const unsigned short*)values_v;
        #pragma unroll 4
        for (int j = 0; j < 125; ++j){
            const int t = wave + 8*j;
            const float a = es[t];
            const unsigned int v2 = *((const unsigned int*)(vals + ((size_t)t*NB + n)*VS) + lane);
            cax += a * __uint_as_float(v2 << 16);
            cay += a * __uint_as_float(v2 & 0xffff0000u);
        }
    } else {
        const float* vals = (const float*)values_v;
        #pragma unroll 4
        for (int j = 0; j < 125; ++j){
            const int t = wave + 8*j;
            const float a = es[t];
            const float2 v2 = *((const float2*)(vals + ((size_t)t*NB + n)*VS) + lane);
            cax += a * v2.x;
            cay += a * v2.y;
        }
    }
    cpart[wave][lane*2]   = cax;
    cpart[wave][lane*2+1] = cay;
    __syncthreads();

    if (tid < 128) {
        float cv = 0.0f;
        #pragma unroll
        for (int w=0; w<8; ++w) cv += cpart[w][tid];
        ctx[n*VS + tid] = cv;
        cat[tid]        = h3[n*KS + tid];
        cat[128 + tid]  = cv;
    }
    __syncthreads();

    // mid = [h3,ctx] @ linW^T + linb ; two threads per output (split K)
    if (tid < 256) {
        const int o  = tid >> 1;
        const int kh = (tid & 1) * 128;
        const float* w = linW + o*(KS+VS) + kh;
        float a = 0.0f;
        #pragma unroll 8
        for (int k=0; k<128; ++k) a += w[k]*cat[kh+k];
        a += __shfl_xor(a, 1, 64);
        if (!(tid & 1)) mid[o] = a + linb[o];
    }
    __syncthreads();

    if (tid < VOCAB) {
        float a = charb[tid];
        const float* w = charW + tid*KS;
        #pragma unroll 8
        for (int k=0; k<KS; ++k) a += w[k]*mid[k];
        out[((size_t)n*MAXLEN + step)*VOCAB + tid] = a;
    }
}

extern "C" void kernel_launch(void* const* d_in, const int* in_sizes, int n_in,
                              void* d_out, int out_size, void* d_ws, size_t ws_size,
                              hipStream_t stream)
{
    const float* keys   = (const float*)d_in[0];
    const float* values = (const float*)d_in[1];
    const int*   seqlen = (const int*)  d_in[2];
    const int*   text   = (const int*)  d_in[3];
    const float* embW   = (const float*)d_in[4];
    const float* w_ih1  = (const float*)d_in[5];
    const float* w_hh1  = (const float*)d_in[6];
    const float* b_ih1  = (const float*)d_in[7];
    const float* b_hh1  = (const float*)d_in[8];
    const float* w_ih2  = (const float*)d_in[9];
    const float* w_hh2  = (const float*)d_in[10];
    const float* b_ih2  = (const float*)d_in[11];
    const float* b_hh2  = (const float*)d_in[12];
    const float* w_ih3  = (const float*)d_in[13];
    const float* w_hh3  = (const float*)d_in[14];
    const float* b_ih3  = (const float*)d_in[15];
    const float* b_hh3  = (const float*)d_in[16];
    const float* linW   = (const float*)d_in[17];
    const float* linb   = (const float*)d_in[18];
    const float* charW  = (const float*)d_in[19];
    const float* charb  = (const float*)d_in[20];
    float* out = (float*)d_out;
    float* ws  = (float*)d_ws;

    float* h1  = ws;              // 2*NH
    float* c1  = h1 + 2*NH;       // NH
    float* h2  = c1 + NH;         // 2*NH
    float* c2  = h2 + 2*NH;       // NH
    float* h3  = c2 + NH;         // 2*NK
    float* c3  = h3 + 2*NK;       // NK
    float* ctx = c3 + NK;         // NK

    const bool use_bf16 = (ws_size >= STATE_BYTES + VBF_BYTES);
    unsigned short* vals_bf = (unsigned short*)((char*)d_ws + STATE_BYTES);

    init_kernel<<<(WS_TOTAL + 255)/256, 256, 0, stream>>>(ws, values);
    if (use_bf16) {
        const int n4 = TT*NB*VS/4;   // 8,192,000
        conv_bf16_kernel<<<(n4 + 255)/256, 256, 0, stream>>>(values, vals_bf, n4);
    }

    for (int t = 0; t < MAXLEN; ++t) {
        const int cur = t & 1, nxt = cur ^ 1;
        lstm_kernel<HID, EMB+VS, HID, 0><<<dim3(HID/16, NB/64), 256, 0, stream>>>(
            w_ih1, w_hh1, b_ih1, b_hh1, ctx, embW, text, t,
            h1 + cur*NH, h1 + nxt*NH, c1);
        lstm_kernel<HID, HID, HID, 1><<<dim3(HID/16, NB/64), 256, 0, stream>>>(
            w_ih2, w_hh2, b_ih2, b_hh2, h1 + nxt*NH, nullptr, nullptr, t,
            h2 + cur*NH, h2 + nxt*NH, c2);
        lstm_kernel<KS, HID, KS, 1><<<dim3(KS/16, NB/64), 256, 0, stream>>>(
            w_ih3, w_hh3, b_ih3, b_hh3, h2 + nxt*NH, nullptr, nullptr, t,
            h3 + cur*NK, h3 + nxt*NK, c3);
        if (use_bf16)
            attn_pred_kernel<1><<<NB, 512, 0, stream>>>(
                keys, vals_bf, seqlen, h3 + nxt*NK,
                linW, linb, charW, charb, ctx, out, t);
        else
            attn_pred_kernel<0><<<NB, 512, 0, stream>>>(
                keys, values, seqlen, h3 + nxt*NK,
                linW, linb, charW, charb, ctx, out, t);
    }
}